// Round 1
// baseline (856.805 us; speedup 1.0000x reference)
//
#include <hip/hip_runtime.h>
#include <cstdint>

// ---------------------------------------------------------------------------
// Problem constants
// ---------------------------------------------------------------------------
#define Bv   4
#define Nv   1024
#define Cv   1024
#define Hv   16
#define Iv   77
#define IDv  768
#define HDv  64
#define HIDv 4096
#define Sv   (Iv + Nv)      // 1101
#define BIv  (Bv * Iv)      // 308
#define BSv  (Bv * Sv)      // 4404
#define BNv  (Bv * Nv)      // 4096

typedef __bf16 bf16x8_t __attribute__((ext_vector_type(8)));
typedef float  f32x4_t  __attribute__((ext_vector_type(4)));

__device__ inline f32x4_t zero4() { f32x4_t z; z[0]=0.f; z[1]=0.f; z[2]=0.f; z[3]=0.f; return z; }

// float -> bf16, round-nearest-even
__device__ inline unsigned short f2bf(float f) {
    unsigned int u = __builtin_bit_cast(unsigned int, f);
    u = (u + 0x7fffu + ((u >> 16) & 1u)) >> 16;
    return (unsigned short)u;
}

__device__ inline float gelu_f(float x) {
    return 0.5f * x * (1.0f + erff(x * 0.70710678118654752440f));
}

// async global(16B/lane) -> LDS  (dest = wave-uniform base + lane*16)
__device__ inline void gload_lds16(const unsigned short* g, unsigned short* l) {
    __builtin_amdgcn_global_load_lds(
        (__attribute__((address_space(1))) void*)(unsigned long long)(const void*)g,
        (__attribute__((address_space(3))) void*)(unsigned long long)(const void*)l,
        16, 0, 0);
}

// ---------------------------------------------------------------------------
// float -> bf16 convert (4 elems / thread)
// ---------------------------------------------------------------------------
__global__ __launch_bounds__(256) void cvt_kernel(const float* __restrict__ in,
                                                  unsigned short* __restrict__ out, int n4) {
    int i = blockIdx.x * 256 + threadIdx.x;
    if (i < n4) {
        float4 v = ((const float4*)in)[i];
        ushort4 o;
        o.x = f2bf(v.x); o.y = f2bf(v.y); o.z = f2bf(v.z); o.w = f2bf(v.w);
        ((ushort4*)out)[i] = o;
    }
}

// qkv_bias = [q_bias, 0, v_bias]
__global__ __launch_bounds__(256) void build_qkvb_kernel(const float* __restrict__ qb,
                                                         const float* __restrict__ vb,
                                                         float* __restrict__ out) {
    int i = blockIdx.x * 256 + threadIdx.x;
    if (i < 3 * Cv) {
        float v = 0.f;
        if (i < Cv) v = qb[i];
        else if (i >= 2 * Cv) v = vb[i - 2 * Cv];
        out[i] = v;
    }
}

// scatter kv rows [BI, C] bf16 into cat rows b*S + i
__global__ __launch_bounds__(256) void scatter_kv_kernel(const unsigned short* __restrict__ kv,
                                                         unsigned short* __restrict__ cat) {
    int r = blockIdx.x;                 // 0..BI-1
    int b = r / Iv, i = r % Iv;
    const uint2* src = (const uint2*)(kv + (size_t)r * Cv);
    uint2* dst = (uint2*)(cat + (size_t)(b * Sv + i) * Cv);
    dst[threadIdx.x] = src[threadIdx.x];   // 256 * 8B = 2048B = 1024 bf16
}

// ---------------------------------------------------------------------------
// LayerNorm (fp32 in) -> bf16 out, one row per block.
// out row index = (r/div)*stride + r%div + off
// ---------------------------------------------------------------------------
__global__ __launch_bounds__(256) void ln_kernel(const float* __restrict__ in,
                                                 const float* __restrict__ w,
                                                 const float* __restrict__ bvec,
                                                 unsigned short* __restrict__ out,
                                                 int cols, float invcols,
                                                 int div_, int stride_, int off_) {
    const int r = blockIdx.x;
    const int tid = threadIdx.x;
    const float* row = in + (size_t)r * cols;
    float s = 0.f, s2 = 0.f;
    for (int c = tid * 4; c < cols; c += 1024) {
        float4 v = *(const float4*)(row + c);
        s  += v.x + v.y + v.z + v.w;
        s2 += v.x * v.x + v.y * v.y + v.z * v.z + v.w * v.w;
    }
#pragma unroll
    for (int o2 = 32; o2 > 0; o2 >>= 1) { s += __shfl_down(s, o2); s2 += __shfl_down(s2, o2); }
    __shared__ float sh[10];
    const int lane = tid & 63, wave = tid >> 6;
    if (lane == 0) { sh[wave] = s; sh[4 + wave] = s2; }
    __syncthreads();
    if (tid == 0) {
        float S1 = sh[0] + sh[1] + sh[2] + sh[3];
        float S2 = sh[4] + sh[5] + sh[6] + sh[7];
        float mean = S1 * invcols;
        float var  = S2 * invcols - mean * mean;
        sh[8] = mean;
        sh[9] = rsqrtf(var + 1e-5f);
    }
    __syncthreads();
    const float mean = sh[8], rstd = sh[9];
    unsigned short* orow = out + (size_t)((r / div_) * stride_ + (r % div_) + off_) * cols;
    for (int c = tid * 4; c < cols; c += 1024) {
        float4 v  = *(const float4*)(row + c);
        float4 wv = *(const float4*)(w + c);
        float4 bv = *(const float4*)(bvec + c);
        ushort4 o;
        o.x = f2bf((v.x - mean) * rstd * wv.x + bv.x);
        o.y = f2bf((v.y - mean) * rstd * wv.y + bv.y);
        o.z = f2bf((v.z - mean) * rstd * wv.z + bv.z);
        o.w = f2bf((v.w - mean) * rstd * wv.w + bv.w);
        *(ushort4*)(orow + c) = o;
    }
}

// ---------------------------------------------------------------------------
// GEMM: O[m,n] = epilogue( sum_k A[m,k]*W[n,k] + bias[n] )
// A [M,K] bf16 row-major, W [N,K] bf16 row-major. 128x128 tile, BK=32,
// 4 waves each 64x64 (4x4 mfma_f32_16x16x32_bf16), global_load_lds staging.
// MODE 0: out bf16 = v            MODE 1: out bf16 = gelu(v)
// MODE 2: out f32  = resid + scale[n]*v
// MODE 3: out f32 += scale[0]*v
// ---------------------------------------------------------------------------
template <int MODE>
__global__ __launch_bounds__(256) void gemm_bf16_kernel(
        const unsigned short* __restrict__ A,
        const unsigned short* __restrict__ W,
        const float* __restrict__ bias,
        void* __restrict__ outp,
        const float* __restrict__ resid,
        const float* __restrict__ scale,
        int M, int N, int K) {
    __shared__ unsigned short As[128 * 32];
    __shared__ unsigned short Bs[128 * 32];
    const int tid  = threadIdx.x;
    const int lane = tid & 63;
    const int wave = tid >> 6;
    const int m16  = lane & 15;
    const int g4   = lane >> 4;
    const int n0 = blockIdx.x * 128;
    const int m0 = blockIdx.y * 128;
    const int wm = (wave >> 1) * 64;
    const int wn = (wave & 1) * 64;

    // staging geometry: chunk c covers row c>>2, cols (c&3)*8 .. +7 (LDS elem c*8)
    const int r0  = tid >> 2;
    const int cc0 = (tid & 3) * 8;
    int am0 = m0 + r0;       if (am0 > M - 1) am0 = M - 1;
    int am1 = m0 + r0 + 64;  if (am1 > M - 1) am1 = M - 1;
    const unsigned short* agp0 = A + (size_t)am0 * K + cc0;
    const unsigned short* agp1 = A + (size_t)am1 * K + cc0;
    const unsigned short* bgp0 = W + (size_t)(n0 + r0) * K + cc0;
    const unsigned short* bgp1 = W + (size_t)(n0 + r0 + 64) * K + cc0;
    unsigned short* lA0 = As + wave * 512;
    unsigned short* lA1 = As + 2048 + wave * 512;
    unsigned short* lB0 = Bs + wave * 512;
    unsigned short* lB1 = Bs + 2048 + wave * 512;

    f32x4_t acc[4][4];
#pragma unroll
    for (int mi = 0; mi < 4; ++mi)
#pragma unroll
        for (int ni = 0; ni < 4; ++ni) acc[mi][ni] = zero4();

    for (int k0 = 0; k0 < K; k0 += 32) {
        gload_lds16(agp0, lA0);
        gload_lds16(agp1, lA1);
        gload_lds16(bgp0, lB0);
        gload_lds16(bgp1, lB1);
        agp0 += 32; agp1 += 32; bgp0 += 32; bgp1 += 32;
        __syncthreads();
        bf16x8_t af[4], bfr[4];
#pragma unroll
        for (int mi = 0; mi < 4; ++mi)
            af[mi] = *(const bf16x8_t*)&As[(wm + mi * 16 + m16) * 32 + g4 * 8];
#pragma unroll
        for (int ni = 0; ni < 4; ++ni)
            bfr[ni] = *(const bf16x8_t*)&Bs[(wn + ni * 16 + m16) * 32 + g4 * 8];
#pragma unroll
        for (int mi = 0; mi < 4; ++mi)
#pragma unroll
            for (int ni = 0; ni < 4; ++ni)
                acc[mi][ni] = __builtin_amdgcn_mfma_f32_16x16x32_bf16(af[mi], bfr[ni], acc[mi][ni], 0, 0, 0);
        __syncthreads();
    }

    const float gatev = (MODE == 3) ? scale[0] : 0.f;
#pragma unroll
    for (int mi = 0; mi < 4; ++mi) {
        const int rowb = m0 + wm + mi * 16 + g4 * 4;
#pragma unroll
        for (int ni = 0; ni < 4; ++ni) {
            const int col = n0 + wn + ni * 16 + m16;
            const float bv = bias[col];
#pragma unroll
            for (int i = 0; i < 4; ++i) {
                const int r = rowb + i;
                if (r < M) {
                    const size_t idx = (size_t)r * N + col;
                    const float v = acc[mi][ni][i] + bv;
                    if constexpr (MODE == 0) {
                        ((unsigned short*)outp)[idx] = f2bf(v);
                    } else if constexpr (MODE == 1) {
                        ((unsigned short*)outp)[idx] = f2bf(gelu_f(v));
                    } else if constexpr (MODE == 2) {
                        ((float*)outp)[idx] = resid[idx] + scale[col] * v;
                    } else {
                        ((float*)outp)[idx] += gatev * v;
                    }
                }
            }
        }
    }
}

// ---------------------------------------------------------------------------
// Flash attention. qkv bf16 [B, S, 3, H, HD]. Output o bf16 [B*N, C].
// Block: 64 queries (4 waves x 16 rows), loops over S in tiles of 64.
// grid = (N/64, B*H)
// ---------------------------------------------------------------------------
__global__ __launch_bounds__(256) void attn_kernel(const unsigned short* __restrict__ qkv,
                                                   unsigned short* __restrict__ o) {
    __shared__ unsigned short Ks[64 * 64];    // [key][d]
    __shared__ unsigned short Vts[64 * 64];   // [d][key]
    __shared__ unsigned short Qs[64 * 64];    // [qrow][d]
    __shared__ unsigned short Ps[4][16 * 64]; // per-wave P: [qrow16][key64]

    const int tid  = threadIdx.x;
    const int lane = tid & 63;
    const int wave = tid >> 6;
    const int m16  = lane & 15;
    const int g4   = lane >> 4;
    const int qt = blockIdx.x;
    const int bh = blockIdx.y;
    const int b = bh >> 4;   // / H
    const int h = bh & 15;   // % H

    // stage Q tile (64 rows x 64 d)
#pragma unroll
    for (int j = 0; j < 2; ++j) {
        int c = j * 256 + tid;
        int r = c >> 3, d8 = (c & 7) * 8;
        int s = Iv + qt * 64 + r;
        const unsigned short* src = qkv + ((size_t)((b * Sv + s) * 3)) * Cv + h * HDv + d8;
        *(uint4*)(&Qs[r * 64 + d8]) = *(const uint4*)src;
    }
    __syncthreads();
    const bf16x8_t qf0 = *(const bf16x8_t*)&Qs[(wave * 16 + m16) * 64 + g4 * 8];
    const bf16x8_t qf1 = *(const bf16x8_t*)&Qs[(wave * 16 + m16) * 64 + 32 + g4 * 8];

    f32x4_t oacc[4];
#pragma unroll
    for (int di = 0; di < 4; ++di) oacc[di] = zero4();
    float mrow[4] = {-1e30f, -1e30f, -1e30f, -1e30f};
    float lrow[4] = {0.f, 0.f, 0.f, 0.f};

    const int NT = (Sv + 63) / 64;   // 18
    for (int st = 0; st < NT; ++st) {
        // stage K tile + transposed V tile
#pragma unroll
        for (int j = 0; j < 2; ++j) {
            int c = j * 256 + tid;
            int r = c >> 3, d8 = (c & 7) * 8;
            int s = st * 64 + r; if (s >= Sv) s = Sv - 1;
            size_t base = ((size_t)((b * Sv + s) * 3)) * Cv + h * HDv + d8;
            *(uint4*)(&Ks[r * 64 + d8]) = *(const uint4*)(qkv + base + Cv);
            uint4 vv = *(const uint4*)(qkv + base + 2 * Cv);
            const unsigned short* vp = (const unsigned short*)&vv;
#pragma unroll
            for (int e = 0; e < 8; ++e) Vts[(d8 + e) * 64 + r] = vp[e];
        }
        __syncthreads();

        // scores = Q @ K^T   (16 q-rows per wave x 64 keys)
        f32x4_t sc[4];
#pragma unroll
        for (int ni = 0; ni < 4; ++ni) {
            bf16x8_t k0 = *(const bf16x8_t*)&Ks[(ni * 16 + m16) * 64 + g4 * 8];
            bf16x8_t k1 = *(const bf16x8_t*)&Ks[(ni * 16 + m16) * 64 + 32 + g4 * 8];
            f32x4_t z = zero4();
            z = __builtin_amdgcn_mfma_f32_16x16x32_bf16(qf0, k0, z, 0, 0, 0);
            z = __builtin_amdgcn_mfma_f32_16x16x32_bf16(qf1, k1, z, 0, 0, 0);
            sc[ni] = z;
        }

        // online softmax per q-row (row = g4*4 + i, value lanes share g4 group)
#pragma unroll
        for (int i = 0; i < 4; ++i) {
            float rmax = -1e30f;
#pragma unroll
            for (int ni = 0; ni < 4; ++ni) {
                int key = st * 64 + ni * 16 + m16;
                float v = sc[ni][i] * 0.125f;          // HD^-0.5
                v = (key < Sv) ? v : -1e30f;
                sc[ni][i] = v;
                rmax = fmaxf(rmax, v);
            }
#pragma unroll
            for (int o2 = 1; o2 < 16; o2 <<= 1) rmax = fmaxf(rmax, __shfl_xor(rmax, o2));
            float mnew  = fmaxf(mrow[i], rmax);
            float alpha = __expf(mrow[i] - mnew);
            mrow[i] = mnew;
            float rsum = 0.f;
#pragma unroll
            for (int ni = 0; ni < 4; ++ni) {
                float p = __expf(sc[ni][i] - mnew);
                sc[ni][i] = p;
                rsum += p;
            }
#pragma unroll
            for (int o2 = 1; o2 < 16; o2 <<= 1) rsum += __shfl_xor(rsum, o2);
            lrow[i] = lrow[i] * alpha + rsum;
#pragma unroll
            for (int di = 0; di < 4; ++di) oacc[di][i] *= alpha;
#pragma unroll
            for (int ni = 0; ni < 4; ++ni)
                Ps[wave][(g4 * 4 + i) * 64 + ni * 16 + m16] = f2bf(sc[ni][i]);
        }
        __syncthreads();   // Ps visible to whole wave (and block)

        // O += P @ V
        const bf16x8_t p0 = *(const bf16x8_t*)&Ps[wave][m16 * 64 + g4 * 8];
        const bf16x8_t p1 = *(const bf16x8_t*)&Ps[wave][m16 * 64 + 32 + g4 * 8];
#pragma unroll
        for (int di = 0; di < 4; ++di) {
            bf16x8_t v0 = *(const bf16x8_t*)&Vts[(di * 16 + m16) * 64 + g4 * 8];
            bf16x8_t v1 = *(const bf16x8_t*)&Vts[(di * 16 + m16) * 64 + 32 + g4 * 8];
            oacc[di] = __builtin_amdgcn_mfma_f32_16x16x32_bf16(p0, v0, oacc[di], 0, 0, 0);
            oacc[di] = __builtin_amdgcn_mfma_f32_16x16x32_bf16(p1, v1, oacc[di], 0, 0, 0);
        }
        __syncthreads();   // before next staging overwrites Ks/Vts
    }

    // normalize + store
#pragma unroll
    for (int i = 0; i < 4; ++i) {
        float inv = 1.0f / lrow[i];
        int q = qt * 64 + wave * 16 + g4 * 4 + i;
        size_t row = (size_t)(b * Nv + q) * Cv + h * HDv;
#pragma unroll
        for (int di = 0; di < 4; ++di)
            o[row + di * 16 + m16] = f2bf(oacc[di][i] * inv);
    }
}

// ---------------------------------------------------------------------------
// Launcher
// ---------------------------------------------------------------------------
extern "C" void kernel_launch(void* const* d_in, const int* in_sizes, int n_in,
                              void* d_out, int out_size, void* d_ws, size_t ws_size,
                              hipStream_t stream) {
    (void)in_sizes; (void)n_in; (void)out_size; (void)ws_size;
    const float* x       = (const float*)d_in[0];
    const float* instr   = (const float*)d_in[1];
    const float* norm1_w = (const float*)d_in[2];
    const float* norm1_b = (const float*)d_in[3];
    const float* qkv_w   = (const float*)d_in[4];
    const float* q_bias  = (const float*)d_in[5];
    const float* v_bias  = (const float*)d_in[6];
    const float* proj_w  = (const float*)d_in[7];
    const float* proj_b  = (const float*)d_in[8];
    const float* gamma_1 = (const float*)d_in[9];
    const float* gamma_2 = (const float*)d_in[10];
    const float* norm2_w = (const float*)d_in[11];
    const float* norm2_b = (const float*)d_in[12];
    const float* fc1_w   = (const float*)d_in[13];
    const float* fc1_b   = (const float*)d_in[14];
    const float* fc2_w   = (const float*)d_in[15];
    const float* fc2_b   = (const float*)d_in[16];
    const float* pfc1_w  = (const float*)d_in[17];
    const float* pfc1_b  = (const float*)d_in[18];
    const float* pfc2_w  = (const float*)d_in[19];
    const float* pfc2_b  = (const float*)d_in[20];
    const float* gate    = (const float*)d_in[21];
    const float* ir_ln_w = (const float*)d_in[22];
    const float* ir_ln_b = (const float*)d_in[23];
    const float* ir_l1_w = (const float*)d_in[24];
    const float* ir_l1_b = (const float*)d_in[25];
    const float* ir_l2_w = (const float*)d_in[26];
    const float* ir_l2_b = (const float*)d_in[27];
    float* out = (float*)d_out;

    char* ws = (char*)d_ws;
    size_t off = 0;
    auto alloc = [&](size_t bytes) -> char* {
        char* p = ws + off;
        off += (bytes + 255) & ~(size_t)255;
        return p;
    };
    unsigned short* w_qkv  = (unsigned short*)alloc((size_t)3 * Cv * Cv * 2);
    unsigned short* w_proj = (unsigned short*)alloc((size_t)Cv * Cv * 2);
    unsigned short* w_fc1  = (unsigned short*)alloc((size_t)HIDv * Cv * 2);
    unsigned short* w_fc2  = (unsigned short*)alloc((size_t)Cv * HIDv * 2);
    unsigned short* w_pfc1 = (unsigned short*)alloc((size_t)HIDv * Cv * 2);
    unsigned short* w_pfc2 = (unsigned short*)alloc((size_t)Cv * HIDv * 2);
    unsigned short* w_ir1  = (unsigned short*)alloc((size_t)Cv * IDv * 2);
    unsigned short* w_ir2  = (unsigned short*)alloc((size_t)Cv * Cv * 2);
    float*          qkvb   = (float*)alloc((size_t)3 * Cv * 4);
    unsigned short* irln   = (unsigned short*)alloc((size_t)BIv * IDv * 2);
    unsigned short* h1     = (unsigned short*)alloc((size_t)BIv * Cv * 2);
    unsigned short* kvtmp  = (unsigned short*)alloc((size_t)BIv * Cv * 2);
    unsigned short* cat    = (unsigned short*)alloc((size_t)BSv * Cv * 2);
    unsigned short* qkvbuf = (unsigned short*)alloc((size_t)BSv * 3 * Cv * 2);
    unsigned short* obuf   = (unsigned short*)alloc((size_t)BNv * Cv * 2);
    float*          x1     = (float*)alloc((size_t)BNv * Cv * 4);
    unsigned short* ybuf   = (unsigned short*)alloc((size_t)BNv * Cv * 2);
    unsigned short* gbuf   = (unsigned short*)alloc((size_t)BNv * HIDv * 2);

    auto cvt = [&](const float* src, unsigned short* dst, size_t n) {
        int n4 = (int)(n / 4);
        cvt_kernel<<<(n4 + 255) / 256, 256, 0, stream>>>(src, dst, n4);
    };
    cvt(qkv_w,  w_qkv,  (size_t)3 * Cv * Cv);
    cvt(proj_w, w_proj, (size_t)Cv * Cv);
    cvt(fc1_w,  w_fc1,  (size_t)HIDv * Cv);
    cvt(fc2_w,  w_fc2,  (size_t)Cv * HIDv);
    cvt(pfc1_w, w_pfc1, (size_t)HIDv * Cv);
    cvt(pfc2_w, w_pfc2, (size_t)Cv * HIDv);
    cvt(ir_l1_w, w_ir1, (size_t)Cv * IDv);
    cvt(ir_l2_w, w_ir2, (size_t)Cv * Cv);

    build_qkvb_kernel<<<12, 256, 0, stream>>>(q_bias, v_bias, qkvb);

    // instruct branch: LN -> Linear+GELU -> Linear
    ln_kernel<<<BIv, 256, 0, stream>>>(instr, ir_ln_w, ir_ln_b, irln,
                                       IDv, 1.0f / IDv, 1 << 28, 0, 0);
    // LN1 writes directly into cat rows b*S + I + n
    ln_kernel<<<BNv, 256, 0, stream>>>(x, norm1_w, norm1_b, cat,
                                       Cv, 1.0f / Cv, Nv, Sv, Iv);
    gemm_bf16_kernel<1><<<dim3(Cv / 128, (BIv + 127) / 128), 256, 0, stream>>>(
        irln, w_ir1, ir_l1_b, h1, nullptr, nullptr, BIv, Cv, IDv);
    gemm_bf16_kernel<0><<<dim3(Cv / 128, (BIv + 127) / 128), 256, 0, stream>>>(
        h1, w_ir2, ir_l2_b, kvtmp, nullptr, nullptr, BIv, Cv, Cv);
    scatter_kv_kernel<<<BIv, 256, 0, stream>>>(kvtmp, cat);

    // QKV projection over cat [BS, C] -> [BS, 3C]
    gemm_bf16_kernel<0><<<dim3(3 * Cv / 128, (BSv + 127) / 128), 256, 0, stream>>>(
        cat, w_qkv, qkvb, qkvbuf, nullptr, nullptr, BSv, 3 * Cv, Cv);

    // attention
    attn_kernel<<<dim3(Nv / 64, Bv * Hv), 256, 0, stream>>>(qkvbuf, obuf);

    // proj + LayerScale residual: x1 = x + gamma_1*(o@proj^T + b)
    gemm_bf16_kernel<2><<<dim3(Cv / 128, BNv / 128), 256, 0, stream>>>(
        obuf, w_proj, proj_b, x1, x, gamma_1, BNv, Cv, Cv);

    // LN2
    ln_kernel<<<BNv, 256, 0, stream>>>(x1, norm2_w, norm2_b, ybuf,
                                       Cv, 1.0f / Cv, 1 << 28, 0, 0);

    // mlp branch: d_out = x1 + gamma_2*(gelu(y@fc1)@fc2 + b)
    gemm_bf16_kernel<1><<<dim3(HIDv / 128, BNv / 128), 256, 0, stream>>>(
        ybuf, w_fc1, fc1_b, gbuf, nullptr, nullptr, BNv, HIDv, Cv);
    gemm_bf16_kernel<2><<<dim3(Cv / 128, BNv / 128), 256, 0, stream>>>(
        gbuf, w_fc2, fc2_b, out, x1, gamma_2, BNv, Cv, HIDv);

    // parallel mlp branch: d_out += gate*(gelu(y@pfc1)@pfc2 + b)
    gemm_bf16_kernel<1><<<dim3(HIDv / 128, BNv / 128), 256, 0, stream>>>(
        ybuf, w_pfc1, pfc1_b, gbuf, nullptr, nullptr, BNv, HIDv, Cv);
    gemm_bf16_kernel<3><<<dim3(Cv / 128, BNv / 128), 256, 0, stream>>>(
        gbuf, w_pfc2, pfc2_b, out, nullptr, gate, BNv, Cv, HIDv);
}

// Round 2
// 735.484 us; speedup vs baseline: 1.1650x; 1.1650x over previous
//
#include <hip/hip_runtime.h>
#include <cstdint>

// ---------------------------------------------------------------------------
// Problem constants
// ---------------------------------------------------------------------------
#define Bv   4
#define Nv   1024
#define Cv   1024
#define Hv   16
#define Iv   77
#define IDv  768
#define HDv  64
#define HIDv 4096
#define Sv   (Iv + Nv)      // 1101
#define BIv  (Bv * Iv)      // 308
#define BSv  (Bv * Sv)      // 4404
#define BNv  (Bv * Nv)      // 4096
#define SPADv 1152          // 18*64, zero-padded key dim for V^T

typedef __bf16 bf16x8_t __attribute__((ext_vector_type(8)));
typedef float  f32x4_t  __attribute__((ext_vector_type(4)));
typedef unsigned short us8_t __attribute__((ext_vector_type(8)));

__device__ inline f32x4_t zero4() { f32x4_t z; z[0]=0.f; z[1]=0.f; z[2]=0.f; z[3]=0.f; return z; }

// float -> bf16, round-nearest-even
__device__ inline unsigned short f2bf(float f) {
    unsigned int u = __builtin_bit_cast(unsigned int, f);
    u = (u + 0x7fffu + ((u >> 16) & 1u)) >> 16;
    return (unsigned short)u;
}

__device__ inline float gelu_f(float x) {
    return 0.5f * x * (1.0f + erff(x * 0.70710678118654752440f));
}

// async global(16B/lane) -> LDS  (dest = wave-uniform base + lane*16)
__device__ inline void gload_lds16(const unsigned short* g, unsigned short* l) {
    __builtin_amdgcn_global_load_lds(
        (__attribute__((address_space(1))) void*)(unsigned long long)(const void*)g,
        (__attribute__((address_space(3))) void*)(unsigned long long)(const void*)l,
        16, 0, 0);
}

// ---------------------------------------------------------------------------
// Fused float -> bf16 convert for all 8 weight tensors (uint4 granules)
// ---------------------------------------------------------------------------
__global__ __launch_bounds__(256) void cvt8_kernel(
        const float* s0, const float* s1, const float* s2, const float* s3,
        const float* s4, const float* s5, const float* s6, const float* s7,
        unsigned short* d0, unsigned short* d1, unsigned short* d2, unsigned short* d3,
        unsigned short* d4, unsigned short* d5, unsigned short* d6, unsigned short* d7) {
    long i = (long)blockIdx.x * 256 + threadIdx.x;
    const float* src; unsigned short* dst; long off;
    // cumulative uint4 boundaries:
    // qkv 786432 | proj 262144 | fc1 1048576 | fc2 1048576 | pfc1 1048576
    // | pfc2 1048576 | ir1 196608 | ir2 262144
    if (i < 2097152) {
        if (i < 786432)       { src = s0; dst = d0; off = i; }
        else if (i < 1048576) { src = s1; dst = d1; off = i - 786432; }
        else                  { src = s2; dst = d2; off = i - 1048576; }
    } else if (i < 4194304) {
        if (i < 3145728)      { src = s3; dst = d3; off = i - 2097152; }
        else                  { src = s4; dst = d4; off = i - 3145728; }
    } else {
        if (i < 5242880)      { src = s5; dst = d5; off = i - 4194304; }
        else if (i < 5439488) { src = s6; dst = d6; off = i - 5242880; }
        else                  { src = s7; dst = d7; off = i - 5439488; }
    }
    float4 v = ((const float4*)src)[off];
    ushort4 o;
    o.x = f2bf(v.x); o.y = f2bf(v.y); o.z = f2bf(v.z); o.w = f2bf(v.w);
    ((ushort4*)dst)[off] = o;
}

// qkv_bias = [q_bias, 0, v_bias]
__global__ __launch_bounds__(256) void build_qkvb_kernel(const float* __restrict__ qb,
                                                         const float* __restrict__ vb,
                                                         float* __restrict__ out) {
    int i = blockIdx.x * 256 + threadIdx.x;
    if (i < 3 * Cv) {
        float v = 0.f;
        if (i < Cv) v = qb[i];
        else if (i >= 2 * Cv) v = vb[i - 2 * Cv];
        out[i] = v;
    }
}

// scatter kv rows [BI, C] bf16 into cat rows b*S + i
__global__ __launch_bounds__(256) void scatter_kv_kernel(const unsigned short* __restrict__ kv,
                                                         unsigned short* __restrict__ cat) {
    int r = blockIdx.x;                 // 0..BI-1
    int b = r / Iv, i = r % Iv;
    const uint2* src = (const uint2*)(kv + (size_t)r * Cv);
    uint2* dst = (uint2*)(cat + (size_t)(b * Sv + i) * Cv);
    dst[threadIdx.x] = src[threadIdx.x];
}

// ---------------------------------------------------------------------------
// LayerNorm (fp32 in) -> bf16 out, one row per block.
// out row index = (r/div)*stride + r%div + off
// ---------------------------------------------------------------------------
__global__ __launch_bounds__(256) void ln_kernel(const float* __restrict__ in,
                                                 const float* __restrict__ w,
                                                 const float* __restrict__ bvec,
                                                 unsigned short* __restrict__ out,
                                                 int cols, float invcols,
                                                 int div_, int stride_, int off_) {
    const int r = blockIdx.x;
    const int tid = threadIdx.x;
    const float* row = in + (size_t)r * cols;
    float s = 0.f, s2 = 0.f;
    for (int c = tid * 4; c < cols; c += 1024) {
        float4 v = *(const float4*)(row + c);
        s  += v.x + v.y + v.z + v.w;
        s2 += v.x * v.x + v.y * v.y + v.z * v.z + v.w * v.w;
    }
#pragma unroll
    for (int o2 = 32; o2 > 0; o2 >>= 1) { s += __shfl_down(s, o2); s2 += __shfl_down(s2, o2); }
    __shared__ float sh[10];
    const int lane = tid & 63, wave = tid >> 6;
    if (lane == 0) { sh[wave] = s; sh[4 + wave] = s2; }
    __syncthreads();
    if (tid == 0) {
        float S1 = sh[0] + sh[1] + sh[2] + sh[3];
        float S2 = sh[4] + sh[5] + sh[6] + sh[7];
        float mean = S1 * invcols;
        float var  = S2 * invcols - mean * mean;
        sh[8] = mean;
        sh[9] = rsqrtf(var + 1e-5f);
    }
    __syncthreads();
    const float mean = sh[8], rstd = sh[9];
    unsigned short* orow = out + (size_t)((r / div_) * stride_ + (r % div_) + off_) * cols;
    for (int c = tid * 4; c < cols; c += 1024) {
        float4 v  = *(const float4*)(row + c);
        float4 wv = *(const float4*)(w + c);
        float4 bv = *(const float4*)(bvec + c);
        ushort4 o;
        o.x = f2bf((v.x - mean) * rstd * wv.x + bv.x);
        o.y = f2bf((v.y - mean) * rstd * wv.y + bv.y);
        o.z = f2bf((v.z - mean) * rstd * wv.z + bv.z);
        o.w = f2bf((v.w - mean) * rstd * wv.w + bv.w);
        *(ushort4*)(orow + c) = o;
    }
}

// ---------------------------------------------------------------------------
// GEMM: O[m,n] = epilogue( sum_k A[m,k]*W[n,k] + bias[n] )
// Operand-swapped MFMA (A-op = W, B-op = act) so each lane's C/D fragment
// holds 4 CONSECUTIVE output columns -> vectorized epilogue stores.
// MODE 0: out bf16 = v            MODE 1: out bf16 = gelu(v)
// MODE 2: out f32  = resid + scale[n]*v
// MODE 3: out f32 += scale[0]*v
// ---------------------------------------------------------------------------
template <int MODE>
__global__ __launch_bounds__(256) void gemm_bf16_kernel(
        const unsigned short* __restrict__ A,
        const unsigned short* __restrict__ W,
        const float* __restrict__ bias,
        void* __restrict__ outp,
        const float* __restrict__ resid,
        const float* __restrict__ scale,
        int M, int N, int K) {
    __shared__ unsigned short As[128 * 32];
    __shared__ unsigned short Bs[128 * 32];
    const int tid  = threadIdx.x;
    const int lane = tid & 63;
    const int wave = tid >> 6;
    const int m16  = lane & 15;
    const int g4   = lane >> 4;
    const int n0 = blockIdx.x * 128;
    const int m0 = blockIdx.y * 128;
    const int wm = (wave >> 1) * 64;
    const int wn = (wave & 1) * 64;

    const int r0  = tid >> 2;
    const int cc0 = (tid & 3) * 8;
    int am0 = m0 + r0;       if (am0 > M - 1) am0 = M - 1;
    int am1 = m0 + r0 + 64;  if (am1 > M - 1) am1 = M - 1;
    const unsigned short* agp0 = A + (size_t)am0 * K + cc0;
    const unsigned short* agp1 = A + (size_t)am1 * K + cc0;
    const unsigned short* bgp0 = W + (size_t)(n0 + r0) * K + cc0;
    const unsigned short* bgp1 = W + (size_t)(n0 + r0 + 64) * K + cc0;
    unsigned short* lA0 = As + wave * 512;
    unsigned short* lA1 = As + 2048 + wave * 512;
    unsigned short* lB0 = Bs + wave * 512;
    unsigned short* lB1 = Bs + 2048 + wave * 512;

    f32x4_t acc[4][4];
#pragma unroll
    for (int a = 0; a < 4; ++a)
#pragma unroll
        for (int bb = 0; bb < 4; ++bb) acc[a][bb] = zero4();

    for (int k0 = 0; k0 < K; k0 += 32) {
        gload_lds16(agp0, lA0);
        gload_lds16(agp1, lA1);
        gload_lds16(bgp0, lB0);
        gload_lds16(bgp1, lB1);
        agp0 += 32; agp1 += 32; bgp0 += 32; bgp1 += 32;
        __syncthreads();
        bf16x8_t xf[4], wf[4];
#pragma unroll
        for (int bb = 0; bb < 4; ++bb)
            xf[bb] = *(const bf16x8_t*)&As[(wm + bb * 16 + m16) * 32 + g4 * 8];
#pragma unroll
        for (int a = 0; a < 4; ++a)
            wf[a] = *(const bf16x8_t*)&Bs[(wn + a * 16 + m16) * 32 + g4 * 8];
#pragma unroll
        for (int a = 0; a < 4; ++a)
#pragma unroll
            for (int bb = 0; bb < 4; ++bb)
                acc[a][bb] = __builtin_amdgcn_mfma_f32_16x16x32_bf16(wf[a], xf[bb], acc[a][bb], 0, 0, 0);
        __syncthreads();
    }

    const float gatev = (MODE == 3) ? scale[0] : 0.f;
#pragma unroll
    for (int a = 0; a < 4; ++a) {
        const int cb = n0 + wn + a * 16 + g4 * 4;   // 4 consecutive out cols
        const float4 bv4 = *(const float4*)(bias + cb);
#pragma unroll
        for (int bb = 0; bb < 4; ++bb) {
            const int r = m0 + wm + bb * 16 + m16;  // act row
            if (r < M) {
                const size_t idx = (size_t)r * N + cb;
                const float v0 = acc[a][bb][0] + bv4.x;
                const float v1 = acc[a][bb][1] + bv4.y;
                const float v2 = acc[a][bb][2] + bv4.z;
                const float v3 = acc[a][bb][3] + bv4.w;
                if constexpr (MODE == 0) {
                    ushort4 o = {f2bf(v0), f2bf(v1), f2bf(v2), f2bf(v3)};
                    *(ushort4*)((unsigned short*)outp + idx) = o;
                } else if constexpr (MODE == 1) {
                    ushort4 o = {f2bf(gelu_f(v0)), f2bf(gelu_f(v1)),
                                 f2bf(gelu_f(v2)), f2bf(gelu_f(v3))};
                    *(ushort4*)((unsigned short*)outp + idx) = o;
                } else if constexpr (MODE == 2) {
                    float4 res = *(const float4*)(resid + idx);
                    float4 sc4 = *(const float4*)(scale + cb);
                    float4 o = {res.x + sc4.x * v0, res.y + sc4.y * v1,
                                res.z + sc4.z * v2, res.w + sc4.w * v3};
                    *(float4*)((float*)outp + idx) = o;
                } else {
                    float4 cur = *(const float4*)((float*)outp + idx);
                    float4 o = {cur.x + gatev * v0, cur.y + gatev * v1,
                                cur.z + gatev * v2, cur.w + gatev * v3};
                    *(float4*)((float*)outp + idx) = o;
                }
            }
        }
    }
}

// ---------------------------------------------------------------------------
// V^T pre-transpose with baked PV key-permutation.
// vt[bh][d][s'] = V[b][ s = 64*(s'>>6) + truekey(s'&63) ][h][d], zero-padded.
// truekey(p) = (p&32) + 16*((p>>2)&1) + 4*((p&31)>>3) + (p&3)
// ---------------------------------------------------------------------------
__global__ __launch_bounds__(256) void vtrans_kernel(const unsigned short* __restrict__ qkv,
                                                     unsigned short* __restrict__ vt) {
    __shared__ unsigned short Vs[64 * 64];
    const int stile = blockIdx.x;   // 0..17
    const int bh = blockIdx.y;
    const int b = bh >> 4, h = bh & 15;
    const int tid = threadIdx.x;
#pragma unroll
    for (int j = 0; j < 2; ++j) {
        int c = j * 256 + tid;
        int r = c >> 3, d8 = (c & 7) * 8;
        int s = stile * 64 + r;
        uint4 v = {0u, 0u, 0u, 0u};
        if (s < Sv) v = *(const uint4*)(qkv + ((size_t)(b * Sv + s) * 3 + 2) * Cv + h * 64 + d8);
        *(uint4*)&Vs[r * 64 + d8] = v;
    }
    __syncthreads();
    const int d  = tid >> 2;
    const int p0 = (tid & 3) * 16;
    unsigned short tmp[16];
#pragma unroll
    for (int e = 0; e < 16; ++e) {
        int p = p0 + e;
        int s_local = (p & 32) + 16 * ((p >> 2) & 1) + 4 * ((p & 31) >> 3) + (p & 3);
        tmp[e] = Vs[s_local * 64 + d];
    }
    unsigned short* dst = vt + ((size_t)bh * 64 + d) * SPADv + stile * 64 + p0;
    *(uint4*)dst       = *(const uint4*)&tmp[0];
    *(uint4*)(dst + 8) = *(const uint4*)&tmp[8];
}

// ---------------------------------------------------------------------------
// Flash attention, S^T formulation.
// qkv bf16 [B, S, 3, H, HD]; vt bf16 [B*H][64][SPAD] (permuted); o bf16 [B*N, C].
// Block = 64 queries (wave w owns q-subtile w*16+m16); key tiles of 64,
// double-buffered global_load_lds staging with XOR-swizzled chunks.
// grid = (N/64, B*H)
// ---------------------------------------------------------------------------
__global__ __launch_bounds__(256) void attn_kernel(const unsigned short* __restrict__ qkv,
                                                   const unsigned short* __restrict__ vt,
                                                   unsigned short* __restrict__ o) {
    __shared__ unsigned short Qs[64 * 64];
    __shared__ unsigned short Ks[2][64 * 64];
    __shared__ unsigned short Vts[2][64 * 64];

    const int tid  = threadIdx.x;
    const int lane = tid & 63;
    const int wave = tid >> 6;
    const int m16  = lane & 15;
    const int g4   = lane >> 4;
    const int qt = blockIdx.x;
    const int bh = blockIdx.y;
    const int b = bh >> 4, h = bh & 15;

    const int lr = lane >> 3;                       // row within 8-row call
    const int csw = ((lane & 7) ^ lr) * 8;          // swizzled global chunk (elems)
    const int sw7 = m16 & 7;                        // read-side swizzle key

    // stage Q tile: rows wave*16 + j*8 + lr
#pragma unroll
    for (int j = 0; j < 2; ++j) {
        int r = wave * 16 + j * 8 + lr;
        int s = Iv + qt * 64 + r;
        gload_lds16(qkv + ((size_t)(b * Sv + s) * 3) * Cv + h * 64 + csw,
                    &Qs[(wave * 16 + j * 8) * 64]);
    }

    // K/V tile staging (double-buffered)
    auto stage_kv = [&](int st, int buf) {
#pragma unroll
        for (int j = 0; j < 2; ++j) {
            int r = wave * 16 + j * 8 + lr;
            int s = st * 64 + r; if (s > Sv - 1) s = Sv - 1;
            gload_lds16(qkv + ((size_t)(b * Sv + s) * 3 + 1) * Cv + h * 64 + csw,
                        &Ks[buf][(wave * 16 + j * 8) * 64]);
            gload_lds16(vt + ((size_t)bh * 64 + r) * SPADv + st * 64 + csw,
                        &Vts[buf][(wave * 16 + j * 8) * 64]);
        }
    };

    f32x4_t oacc[4];
#pragma unroll
    for (int dt = 0; dt < 4; ++dt) oacc[dt] = zero4();
    float m_run = -1e30f, l_run = 0.f;

    stage_kv(0, 0);
    __syncthreads();

    const bf16x8_t qf0 = *(const bf16x8_t*)&Qs[(wave * 16 + m16) * 64 + ((0 ^ sw7) ^ g4 ^ sw7 ? 0 : 0) + ((g4 ^ sw7) * 8)];
    const bf16x8_t qf1 = *(const bf16x8_t*)&Qs[(wave * 16 + m16) * 64 + (((4 + g4) ^ sw7) * 8)];

    const int NT = (Sv + 63) / 64;   // 18
    for (int st = 0; st < NT; ++st) {
        const int cur = st & 1;
        if (st + 1 < NT) stage_kv(st + 1, cur ^ 1);

        // S^T = K @ Q^T : D[m=key][n=q], 4 key-blocks x (2 d-halves)
        f32x4_t sc[4];
#pragma unroll
        for (int kt = 0; kt < 4; ++kt) {
            bf16x8_t k0 = *(const bf16x8_t*)&Ks[cur][(kt * 16 + m16) * 64 + ((g4 ^ sw7) * 8)];
            bf16x8_t k1 = *(const bf16x8_t*)&Ks[cur][(kt * 16 + m16) * 64 + (((4 + g4) ^ sw7) * 8)];
            f32x4_t z = zero4();
            z = __builtin_amdgcn_mfma_f32_16x16x32_bf16(k0, qf0, z, 0, 0, 0);
            z = __builtin_amdgcn_mfma_f32_16x16x32_bf16(k1, qf1, z, 0, 0, 0);
            sc[kt] = z;
        }

        // online softmax; q = m16 -> all stats are per-lane scalars
        float mx = -1e30f;
#pragma unroll
        for (int kt = 0; kt < 4; ++kt)
#pragma unroll
            for (int r = 0; r < 4; ++r) {
                int key = st * 64 + kt * 16 + g4 * 4 + r;
                float v = sc[kt][r] * 0.125f;
                v = (key < Sv) ? v : -1e30f;
                sc[kt][r] = v;
                mx = fmaxf(mx, v);
            }
        mx = fmaxf(mx, __shfl_xor(mx, 16));
        mx = fmaxf(mx, __shfl_xor(mx, 32));
        const float mnew  = fmaxf(m_run, mx);
        const float alpha = __expf(m_run - mnew);
        m_run = mnew;
        float sum = 0.f;
#pragma unroll
        for (int kt = 0; kt < 4; ++kt)
#pragma unroll
            for (int r = 0; r < 4; ++r) {
                float p = __expf(sc[kt][r] - mnew);
                sc[kt][r] = p;
                sum += p;
            }
        sum += __shfl_xor(sum, 16);
        sum += __shfl_xor(sum, 32);
        l_run = l_run * alpha + sum;
#pragma unroll
        for (int dt = 0; dt < 4; ++dt) oacc[dt] *= alpha;

        // P fragments: lane's own registers (permutation baked into vt)
        us8_t pu0, pu1;
#pragma unroll
        for (int j = 0; j < 8; ++j) {
            pu0[j] = f2bf(sc[(j >> 2)][j & 3]);
            pu1[j] = f2bf(sc[2 + (j >> 2)][j & 3]);
        }
        const bf16x8_t pf0 = __builtin_bit_cast(bf16x8_t, pu0);
        const bf16x8_t pf1 = __builtin_bit_cast(bf16x8_t, pu1);

        // O += V^T-op x P : D[m=d][n=q]
#pragma unroll
        for (int dt = 0; dt < 4; ++dt) {
            bf16x8_t v0 = *(const bf16x8_t*)&Vts[cur][(dt * 16 + m16) * 64 + ((g4 ^ sw7) * 8)];
            bf16x8_t v1 = *(const bf16x8_t*)&Vts[cur][(dt * 16 + m16) * 64 + (((4 + g4) ^ sw7) * 8)];
            oacc[dt] = __builtin_amdgcn_mfma_f32_16x16x32_bf16(v0, pf0, oacc[dt], 0, 0, 0);
            oacc[dt] = __builtin_amdgcn_mfma_f32_16x16x32_bf16(v1, pf1, oacc[dt], 0, 0, 0);
        }
        __syncthreads();
    }

    // normalize + store: q = m16, d = dt*16 + g4*4 + reg (4 contiguous)
    const float inv = 1.0f / l_run;
    const int q = qt * 64 + wave * 16 + m16;
    const size_t row = (size_t)(b * Nv + q) * Cv + h * 64;
#pragma unroll
    for (int dt = 0; dt < 4; ++dt) {
        ushort4 o4 = {f2bf(oacc[dt][0] * inv), f2bf(oacc[dt][1] * inv),
                      f2bf(oacc[dt][2] * inv), f2bf(oacc[dt][3] * inv)};
        *(ushort4*)&o[row + dt * 16 + g4 * 4] = o4;
    }
}

// ---------------------------------------------------------------------------
// Launcher
// ---------------------------------------------------------------------------
extern "C" void kernel_launch(void* const* d_in, const int* in_sizes, int n_in,
                              void* d_out, int out_size, void* d_ws, size_t ws_size,
                              hipStream_t stream) {
    (void)in_sizes; (void)n_in; (void)out_size; (void)ws_size;
    const float* x       = (const float*)d_in[0];
    const float* instr   = (const float*)d_in[1];
    const float* norm1_w = (const float*)d_in[2];
    const float* norm1_b = (const float*)d_in[3];
    const float* qkv_w   = (const float*)d_in[4];
    const float* q_bias  = (const float*)d_in[5];
    const float* v_bias  = (const float*)d_in[6];
    const float* proj_w  = (const float*)d_in[7];
    const float* proj_b  = (const float*)d_in[8];
    const float* gamma_1 = (const float*)d_in[9];
    const float* gamma_2 = (const float*)d_in[10];
    const float* norm2_w = (const float*)d_in[11];
    const float* norm2_b = (const float*)d_in[12];
    const float* fc1_w   = (const float*)d_in[13];
    const float* fc1_b   = (const float*)d_in[14];
    const float* fc2_w   = (const float*)d_in[15];
    const float* fc2_b   = (const float*)d_in[16];
    const float* pfc1_w  = (const float*)d_in[17];
    const float* pfc1_b  = (const float*)d_in[18];
    const float* pfc2_w  = (const float*)d_in[19];
    const float* pfc2_b  = (const float*)d_in[20];
    const float* gate    = (const float*)d_in[21];
    const float* ir_ln_w = (const float*)d_in[22];
    const float* ir_ln_b = (const float*)d_in[23];
    const float* ir_l1_w = (const float*)d_in[24];
    const float* ir_l1_b = (const float*)d_in[25];
    const float* ir_l2_w = (const float*)d_in[26];
    const float* ir_l2_b = (const float*)d_in[27];
    float* out = (float*)d_out;

    char* ws = (char*)d_ws;
    size_t off = 0;
    auto alloc = [&](size_t bytes) -> char* {
        char* p = ws + off;
        off += (bytes + 255) & ~(size_t)255;
        return p;
    };
    unsigned short* w_qkv  = (unsigned short*)alloc((size_t)3 * Cv * Cv * 2);
    unsigned short* w_proj = (unsigned short*)alloc((size_t)Cv * Cv * 2);
    unsigned short* w_fc1  = (unsigned short*)alloc((size_t)HIDv * Cv * 2);
    unsigned short* w_fc2  = (unsigned short*)alloc((size_t)Cv * HIDv * 2);
    unsigned short* w_pfc1 = (unsigned short*)alloc((size_t)HIDv * Cv * 2);
    unsigned short* w_pfc2 = (unsigned short*)alloc((size_t)Cv * HIDv * 2);
    unsigned short* w_ir1  = (unsigned short*)alloc((size_t)Cv * IDv * 2);
    unsigned short* w_ir2  = (unsigned short*)alloc((size_t)Cv * Cv * 2);
    float*          qkvb   = (float*)alloc((size_t)3 * Cv * 4);
    unsigned short* irln   = (unsigned short*)alloc((size_t)BIv * IDv * 2);
    unsigned short* h1     = (unsigned short*)alloc((size_t)BIv * Cv * 2);
    unsigned short* kvtmp  = (unsigned short*)alloc((size_t)BIv * Cv * 2);
    unsigned short* cat    = (unsigned short*)alloc((size_t)BSv * Cv * 2);
    unsigned short* qkvbuf = (unsigned short*)alloc((size_t)BSv * 3 * Cv * 2);
    unsigned short* obuf   = (unsigned short*)alloc((size_t)BNv * Cv * 2);
    float*          x1     = (float*)alloc((size_t)BNv * Cv * 4);
    unsigned short* ybuf   = (unsigned short*)alloc((size_t)BNv * Cv * 2);
    unsigned short* gbuf   = (unsigned short*)alloc((size_t)BNv * HIDv * 2);
    // vt aliases gbuf (gbuf is only used after attention completes)
    unsigned short* vt     = gbuf;

    cvt8_kernel<<<22272, 256, 0, stream>>>(qkv_w, proj_w, fc1_w, fc2_w, pfc1_w, pfc2_w,
                                           ir_l1_w, ir_l2_w,
                                           w_qkv, w_proj, w_fc1, w_fc2, w_pfc1, w_pfc2,
                                           w_ir1, w_ir2);

    build_qkvb_kernel<<<12, 256, 0, stream>>>(q_bias, v_bias, qkvb);

    // instruct branch: LN -> Linear+GELU -> Linear
    ln_kernel<<<BIv, 256, 0, stream>>>(instr, ir_ln_w, ir_ln_b, irln,
                                       IDv, 1.0f / IDv, 1 << 28, 0, 0);
    // LN1 writes directly into cat rows b*S + I + n
    ln_kernel<<<BNv, 256, 0, stream>>>(x, norm1_w, norm1_b, cat,
                                       Cv, 1.0f / Cv, Nv, Sv, Iv);
    gemm_bf16_kernel<1><<<dim3(Cv / 128, (BIv + 127) / 128), 256, 0, stream>>>(
        irln, w_ir1, ir_l1_b, h1, nullptr, nullptr, BIv, Cv, IDv);
    gemm_bf16_kernel<0><<<dim3(Cv / 128, (BIv + 127) / 128), 256, 0, stream>>>(
        h1, w_ir2, ir_l2_b, kvtmp, nullptr, nullptr, BIv, Cv, Cv);
    scatter_kv_kernel<<<BIv, 256, 0, stream>>>(kvtmp, cat);

    // QKV projection over cat [BS, C] -> [BS, 3C]
    gemm_bf16_kernel<0><<<dim3(3 * Cv / 128, (BSv + 127) / 128), 256, 0, stream>>>(
        cat, w_qkv, qkvb, qkvbuf, nullptr, nullptr, BSv, 3 * Cv, Cv);

    // V^T pre-transpose (permuted), then attention
    vtrans_kernel<<<dim3(18, Bv * Hv), 256, 0, stream>>>(qkvbuf, vt);
    attn_kernel<<<dim3(Nv / 64, Bv * Hv), 256, 0, stream>>>(qkvbuf, vt, obuf);

    // proj + LayerScale residual: x1 = x + gamma_1*(o@proj^T + b)
    gemm_bf16_kernel<2><<<dim3(Cv / 128, BNv / 128), 256, 0, stream>>>(
        obuf, w_proj, proj_b, x1, x, gamma_1, BNv, Cv, Cv);

    // LN2
    ln_kernel<<<BNv, 256, 0, stream>>>(x1, norm2_w, norm2_b, ybuf,
                                       Cv, 1.0f / Cv, 1 << 28, 0, 0);

    // mlp branch: d_out = x1 + gamma_2*(gelu(y@fc1)@fc2 + b)
    gemm_bf16_kernel<1><<<dim3(HIDv / 128, BNv / 128), 256, 0, stream>>>(
        ybuf, w_fc1, fc1_b, gbuf, nullptr, nullptr, BNv, HIDv, Cv);
    gemm_bf16_kernel<2><<<dim3(Cv / 128, BNv / 128), 256, 0, stream>>>(
        gbuf, w_fc2, fc2_b, out, x1, gamma_2, BNv, Cv, HIDv);

    // parallel mlp branch: d_out += gate*(gelu(y@pfc1)@pfc2 + b)
    gemm_bf16_kernel<1><<<dim3(HIDv / 128, BNv / 128), 256, 0, stream>>>(
        ybuf, w_pfc1, pfc1_b, gbuf, nullptr, nullptr, BNv, HIDv, Cv);
    gemm_bf16_kernel<3><<<dim3(Cv / 128, BNv / 128), 256, 0, stream>>>(
        gbuf, w_pfc2, pfc2_b, out, nullptr, gate, BNv, Cv, HIDv);
}

// Round 3
// 652.118 us; speedup vs baseline: 1.3139x; 1.1278x over previous
//
#include <hip/hip_runtime.h>
#include <cstdint>

// ---------------------------------------------------------------------------
// Problem constants
// ---------------------------------------------------------------------------
#define Bv   4
#define Nv   1024
#define Cv   1024
#define Hv   16
#define Iv   77
#define IDv  768
#define HDv  64
#define HIDv 4096
#define Sv   (Iv + Nv)      // 1101
#define BIv  (Bv * Iv)      // 308
#define BSv  (Bv * Sv)      // 4404
#define BNv  (Bv * Nv)      // 4096
#define SPADv 1152          // 18*64, zero-padded key dim for V^T

typedef __bf16 bf16x8_t __attribute__((ext_vector_type(8)));
typedef float  f32x4_t  __attribute__((ext_vector_type(4)));
typedef unsigned short us8_t __attribute__((ext_vector_type(8)));

__device__ inline f32x4_t zero4() { f32x4_t z; z[0]=0.f; z[1]=0.f; z[2]=0.f; z[3]=0.f; return z; }

// float -> bf16, round-nearest-even
__device__ inline unsigned short f2bf(float f) {
    unsigned int u = __builtin_bit_cast(unsigned int, f);
    u = (u + 0x7fffu + ((u >> 16) & 1u)) >> 16;
    return (unsigned short)u;
}

__device__ inline float gelu_f(float x) {
    return 0.5f * x * (1.0f + erff(x * 0.70710678118654752440f));
}

// async global(16B/lane) -> LDS  (dest = wave-uniform base + lane*16)
__device__ inline void gload_lds16(const unsigned short* g, unsigned short* l) {
    __builtin_amdgcn_global_load_lds(
        (__attribute__((address_space(1))) void*)(unsigned long long)(const void*)g,
        (__attribute__((address_space(3))) void*)(unsigned long long)(const void*)l,
        16, 0, 0);
}

// ---------------------------------------------------------------------------
// Fused float -> bf16 convert for all 8 weight tensors (uint4 granules)
// ---------------------------------------------------------------------------
__global__ __launch_bounds__(256) void cvt8_kernel(
        const float* s0, const float* s1, const float* s2, const float* s3,
        const float* s4, const float* s5, const float* s6, const float* s7,
        unsigned short* d0, unsigned short* d1, unsigned short* d2, unsigned short* d3,
        unsigned short* d4, unsigned short* d5, unsigned short* d6, unsigned short* d7) {
    long i = (long)blockIdx.x * 256 + threadIdx.x;
    const float* src; unsigned short* dst; long off;
    if (i < 2097152) {
        if (i < 786432)       { src = s0; dst = d0; off = i; }
        else if (i < 1048576) { src = s1; dst = d1; off = i - 786432; }
        else                  { src = s2; dst = d2; off = i - 1048576; }
    } else if (i < 4194304) {
        if (i < 3145728)      { src = s3; dst = d3; off = i - 2097152; }
        else                  { src = s4; dst = d4; off = i - 3145728; }
    } else {
        if (i < 5242880)      { src = s5; dst = d5; off = i - 4194304; }
        else if (i < 5439488) { src = s6; dst = d6; off = i - 5242880; }
        else                  { src = s7; dst = d7; off = i - 5439488; }
    }
    float4 v = ((const float4*)src)[off];
    ushort4 o;
    o.x = f2bf(v.x); o.y = f2bf(v.y); o.z = f2bf(v.z); o.w = f2bf(v.w);
    ((ushort4*)dst)[off] = o;
}

// qkv_bias = [q_bias, 0, v_bias]
__global__ __launch_bounds__(256) void build_qkvb_kernel(const float* __restrict__ qb,
                                                         const float* __restrict__ vb,
                                                         float* __restrict__ out) {
    int i = blockIdx.x * 256 + threadIdx.x;
    if (i < 3 * Cv) {
        float v = 0.f;
        if (i < Cv) v = qb[i];
        else if (i >= 2 * Cv) v = vb[i - 2 * Cv];
        out[i] = v;
    }
}

// scatter kv rows [BI, C] bf16 into cat rows b*S + i
__global__ __launch_bounds__(256) void scatter_kv_kernel(const unsigned short* __restrict__ kv,
                                                         unsigned short* __restrict__ cat) {
    int r = blockIdx.x;
    int b = r / Iv, i = r % Iv;
    const uint2* src = (const uint2*)(kv + (size_t)r * Cv);
    uint2* dst = (uint2*)(cat + (size_t)(b * Sv + i) * Cv);
    dst[threadIdx.x] = src[threadIdx.x];
}

// ---------------------------------------------------------------------------
// LayerNorm (fp32 in) -> bf16 out, one row per block.
// out row index = (r/div)*stride + r%div + off
// ---------------------------------------------------------------------------
__global__ __launch_bounds__(256) void ln_kernel(const float* __restrict__ in,
                                                 const float* __restrict__ w,
                                                 const float* __restrict__ bvec,
                                                 unsigned short* __restrict__ out,
                                                 int cols, float invcols,
                                                 int div_, int stride_, int off_) {
    const int r = blockIdx.x;
    const int tid = threadIdx.x;
    const float* row = in + (size_t)r * cols;
    float s = 0.f, s2 = 0.f;
    for (int c = tid * 4; c < cols; c += 1024) {
        float4 v = *(const float4*)(row + c);
        s  += v.x + v.y + v.z + v.w;
        s2 += v.x * v.x + v.y * v.y + v.z * v.z + v.w * v.w;
    }
#pragma unroll
    for (int o2 = 32; o2 > 0; o2 >>= 1) { s += __shfl_down(s, o2); s2 += __shfl_down(s2, o2); }
    __shared__ float sh[10];
    const int lane = tid & 63, wave = tid >> 6;
    if (lane == 0) { sh[wave] = s; sh[4 + wave] = s2; }
    __syncthreads();
    if (tid == 0) {
        float S1 = sh[0] + sh[1] + sh[2] + sh[3];
        float S2 = sh[4] + sh[5] + sh[6] + sh[7];
        float mean = S1 * invcols;
        float var  = S2 * invcols - mean * mean;
        sh[8] = mean;
        sh[9] = rsqrtf(var + 1e-5f);
    }
    __syncthreads();
    const float mean = sh[8], rstd = sh[9];
    unsigned short* orow = out + (size_t)((r / div_) * stride_ + (r % div_) + off_) * cols;
    for (int c = tid * 4; c < cols; c += 1024) {
        float4 v  = *(const float4*)(row + c);
        float4 wv = *(const float4*)(w + c);
        float4 bv = *(const float4*)(bvec + c);
        ushort4 o;
        o.x = f2bf((v.x - mean) * rstd * wv.x + bv.x);
        o.y = f2bf((v.y - mean) * rstd * wv.y + bv.y);
        o.z = f2bf((v.z - mean) * rstd * wv.z + bv.z);
        o.w = f2bf((v.w - mean) * rstd * wv.w + bv.w);
        *(ushort4*)(orow + c) = o;
    }
}

// ---------------------------------------------------------------------------
// GEMM: O[m,n] = epilogue( sum_k A[m,k]*W[n,k] + bias[n] )
// 128x128 tile, BK=32, double-buffered LDS (ONE barrier per K-iter: stage
// tile k+1 right after the barrier that published tile k).
// Operand-swapped MFMA so each lane's C/D fragment = 4 consecutive columns.
// MODE 0: out bf16 = v     MODE 1: out bf16 = gelu(v)
// MODE 2: out f32  = resid + scale[n]*v
// ---------------------------------------------------------------------------
template <int MODE>
__global__ __launch_bounds__(256) void gemm_bf16_kernel(
        const unsigned short* __restrict__ A,
        const unsigned short* __restrict__ W,
        const float* __restrict__ bias,
        void* __restrict__ outp,
        const float* __restrict__ resid,
        const float* __restrict__ scale,
        int M, int N, int K) {
    __shared__ unsigned short As[2][128 * 32];
    __shared__ unsigned short Bs[2][128 * 32];
    const int tid  = threadIdx.x;
    const int lane = tid & 63;
    const int wave = tid >> 6;
    const int m16  = lane & 15;
    const int g4   = lane >> 4;
    const int n0 = blockIdx.x * 128;
    const int m0 = blockIdx.y * 128;
    const int wm = (wave >> 1) * 64;
    const int wn = (wave & 1) * 64;

    const int r0  = tid >> 2;
    const int cc0 = (tid & 3) * 8;
    int am0 = m0 + r0;       if (am0 > M - 1) am0 = M - 1;
    int am1 = m0 + r0 + 64;  if (am1 > M - 1) am1 = M - 1;
    const unsigned short* agp0 = A + (size_t)am0 * K + cc0;
    const unsigned short* agp1 = A + (size_t)am1 * K + cc0;
    const unsigned short* bgp0 = W + (size_t)(n0 + r0) * K + cc0;
    const unsigned short* bgp1 = W + (size_t)(n0 + r0 + 64) * K + cc0;

    f32x4_t acc[4][4];
#pragma unroll
    for (int a = 0; a < 4; ++a)
#pragma unroll
        for (int bb = 0; bb < 4; ++bb) acc[a][bb] = zero4();

    auto stage = [&](int buf) {
        gload_lds16(agp0, &As[buf][wave * 512]);
        gload_lds16(agp1, &As[buf][2048 + wave * 512]);
        gload_lds16(bgp0, &Bs[buf][wave * 512]);
        gload_lds16(bgp1, &Bs[buf][2048 + wave * 512]);
        agp0 += 32; agp1 += 32; bgp0 += 32; bgp1 += 32;
    };

    stage(0);
    const int NIT = K >> 5;
    for (int it = 0; it < NIT; ++it) {
        const int cur = it & 1;
        __syncthreads();                      // publishes buf `cur`
        if (it + 1 < NIT) stage(cur ^ 1);     // prefetch flies during MFMA phase
        bf16x8_t xf[4], wf[4];
#pragma unroll
        for (int bb = 0; bb < 4; ++bb)
            xf[bb] = *(const bf16x8_t*)&As[cur][(wm + bb * 16 + m16) * 32 + g4 * 8];
#pragma unroll
        for (int a = 0; a < 4; ++a)
            wf[a] = *(const bf16x8_t*)&Bs[cur][(wn + a * 16 + m16) * 32 + g4 * 8];
#pragma unroll
        for (int a = 0; a < 4; ++a)
#pragma unroll
            for (int bb = 0; bb < 4; ++bb)
                acc[a][bb] = __builtin_amdgcn_mfma_f32_16x16x32_bf16(wf[a], xf[bb], acc[a][bb], 0, 0, 0);
    }

#pragma unroll
    for (int a = 0; a < 4; ++a) {
        const int cb = n0 + wn + a * 16 + g4 * 4;
        const float4 bv4 = *(const float4*)(bias + cb);
#pragma unroll
        for (int bb = 0; bb < 4; ++bb) {
            const int r = m0 + wm + bb * 16 + m16;
            if (r < M) {
                const size_t idx = (size_t)r * N + cb;
                const float v0 = acc[a][bb][0] + bv4.x;
                const float v1 = acc[a][bb][1] + bv4.y;
                const float v2 = acc[a][bb][2] + bv4.z;
                const float v3 = acc[a][bb][3] + bv4.w;
                if constexpr (MODE == 0) {
                    ushort4 o = {f2bf(v0), f2bf(v1), f2bf(v2), f2bf(v3)};
                    *(ushort4*)((unsigned short*)outp + idx) = o;
                } else if constexpr (MODE == 1) {
                    ushort4 o = {f2bf(gelu_f(v0)), f2bf(gelu_f(v1)),
                                 f2bf(gelu_f(v2)), f2bf(gelu_f(v3))};
                    *(ushort4*)((unsigned short*)outp + idx) = o;
                } else {
                    float4 res = *(const float4*)(resid + idx);
                    float4 sc4 = *(const float4*)(scale + cb);
                    float4 o = {res.x + sc4.x * v0, res.y + sc4.y * v1,
                                res.z + sc4.z * v2, res.w + sc4.w * v3};
                    *(float4*)((float*)outp + idx) = o;
                }
            }
        }
    }
}

// ---------------------------------------------------------------------------
// Fused dual-weight GEMM (fc1 + pfc1): shared activations A, two weight
// matrices, two gelu outputs. 32 MFMA per wave per barrier.
// ---------------------------------------------------------------------------
__global__ __launch_bounds__(256) void gemm_dualw_kernel(
        const unsigned short* __restrict__ A,
        const unsigned short* __restrict__ W1,
        const unsigned short* __restrict__ W2,
        const float* __restrict__ b1,
        const float* __restrict__ b2,
        unsigned short* __restrict__ out1,
        unsigned short* __restrict__ out2,
        int M, int N, int K) {
    __shared__ unsigned short As[2][128 * 32];
    __shared__ unsigned short B1s[2][128 * 32];
    __shared__ unsigned short B2s[2][128 * 32];
    const int tid  = threadIdx.x;
    const int lane = tid & 63;
    const int wave = tid >> 6;
    const int m16  = lane & 15;
    const int g4   = lane >> 4;
    const int n0 = blockIdx.x * 128;
    const int m0 = blockIdx.y * 128;
    const int wm = (wave >> 1) * 64;
    const int wn = (wave & 1) * 64;

    const int r0  = tid >> 2;
    const int cc0 = (tid & 3) * 8;
    int am0 = m0 + r0;       if (am0 > M - 1) am0 = M - 1;
    int am1 = m0 + r0 + 64;  if (am1 > M - 1) am1 = M - 1;
    const unsigned short* agp0 = A  + (size_t)am0 * K + cc0;
    const unsigned short* agp1 = A  + (size_t)am1 * K + cc0;
    const unsigned short* w1p0 = W1 + (size_t)(n0 + r0) * K + cc0;
    const unsigned short* w1p1 = W1 + (size_t)(n0 + r0 + 64) * K + cc0;
    const unsigned short* w2p0 = W2 + (size_t)(n0 + r0) * K + cc0;
    const unsigned short* w2p1 = W2 + (size_t)(n0 + r0 + 64) * K + cc0;

    f32x4_t acc1[4][4], acc2[4][4];
#pragma unroll
    for (int a = 0; a < 4; ++a)
#pragma unroll
        for (int bb = 0; bb < 4; ++bb) { acc1[a][bb] = zero4(); acc2[a][bb] = zero4(); }

    auto stage = [&](int buf) {
        gload_lds16(agp0, &As[buf][wave * 512]);
        gload_lds16(agp1, &As[buf][2048 + wave * 512]);
        gload_lds16(w1p0, &B1s[buf][wave * 512]);
        gload_lds16(w1p1, &B1s[buf][2048 + wave * 512]);
        gload_lds16(w2p0, &B2s[buf][wave * 512]);
        gload_lds16(w2p1, &B2s[buf][2048 + wave * 512]);
        agp0 += 32; agp1 += 32; w1p0 += 32; w1p1 += 32; w2p0 += 32; w2p1 += 32;
    };

    stage(0);
    const int NIT = K >> 5;
    for (int it = 0; it < NIT; ++it) {
        const int cur = it & 1;
        __syncthreads();
        if (it + 1 < NIT) stage(cur ^ 1);
        bf16x8_t xf[4], w1f[4], w2f[4];
#pragma unroll
        for (int bb = 0; bb < 4; ++bb)
            xf[bb] = *(const bf16x8_t*)&As[cur][(wm + bb * 16 + m16) * 32 + g4 * 8];
#pragma unroll
        for (int a = 0; a < 4; ++a) {
            w1f[a] = *(const bf16x8_t*)&B1s[cur][(wn + a * 16 + m16) * 32 + g4 * 8];
            w2f[a] = *(const bf16x8_t*)&B2s[cur][(wn + a * 16 + m16) * 32 + g4 * 8];
        }
#pragma unroll
        for (int a = 0; a < 4; ++a)
#pragma unroll
            for (int bb = 0; bb < 4; ++bb) {
                acc1[a][bb] = __builtin_amdgcn_mfma_f32_16x16x32_bf16(w1f[a], xf[bb], acc1[a][bb], 0, 0, 0);
                acc2[a][bb] = __builtin_amdgcn_mfma_f32_16x16x32_bf16(w2f[a], xf[bb], acc2[a][bb], 0, 0, 0);
            }
    }

#pragma unroll
    for (int a = 0; a < 4; ++a) {
        const int cb = n0 + wn + a * 16 + g4 * 4;
        const float4 b1v = *(const float4*)(b1 + cb);
        const float4 b2v = *(const float4*)(b2 + cb);
#pragma unroll
        for (int bb = 0; bb < 4; ++bb) {
            const int r = m0 + wm + bb * 16 + m16;
            if (r < M) {
                const size_t idx = (size_t)r * N + cb;
                ushort4 o1 = {f2bf(gelu_f(acc1[a][bb][0] + b1v.x)),
                              f2bf(gelu_f(acc1[a][bb][1] + b1v.y)),
                              f2bf(gelu_f(acc1[a][bb][2] + b1v.z)),
                              f2bf(gelu_f(acc1[a][bb][3] + b1v.w))};
                ushort4 o2 = {f2bf(gelu_f(acc2[a][bb][0] + b2v.x)),
                              f2bf(gelu_f(acc2[a][bb][1] + b2v.y)),
                              f2bf(gelu_f(acc2[a][bb][2] + b2v.z)),
                              f2bf(gelu_f(acc2[a][bb][3] + b2v.w))};
                *(ushort4*)(out1 + idx) = o1;
                *(ushort4*)(out2 + idx) = o2;
            }
        }
    }
}

// ---------------------------------------------------------------------------
// Fused dual-input GEMM (fc2 + pfc2): two (A, W) pairs, one combined epilogue
// out = resid + g2[n]*(v1 + b1[n]) + gate*(v2 + b2[n]),  fp32 out.
// ---------------------------------------------------------------------------
__global__ __launch_bounds__(256) void gemm_dualab_kernel(
        const unsigned short* __restrict__ A1,
        const unsigned short* __restrict__ A2,
        const unsigned short* __restrict__ W1,
        const unsigned short* __restrict__ W2,
        const float* __restrict__ b1,
        const float* __restrict__ b2,
        const float* __restrict__ resid,
        const float* __restrict__ g2v,
        const float* __restrict__ gate,
        float* __restrict__ out,
        int M, int N, int K) {
    __shared__ unsigned short A1s[2][128 * 32];
    __shared__ unsigned short A2s[2][128 * 32];
    __shared__ unsigned short B1s[2][128 * 32];
    __shared__ unsigned short B2s[2][128 * 32];
    const int tid  = threadIdx.x;
    const int lane = tid & 63;
    const int wave = tid >> 6;
    const int m16  = lane & 15;
    const int g4   = lane >> 4;
    const int n0 = blockIdx.x * 128;
    const int m0 = blockIdx.y * 128;
    const int wm = (wave >> 1) * 64;
    const int wn = (wave & 1) * 64;

    const int r0  = tid >> 2;
    const int cc0 = (tid & 3) * 8;
    int am0 = m0 + r0;       if (am0 > M - 1) am0 = M - 1;
    int am1 = m0 + r0 + 64;  if (am1 > M - 1) am1 = M - 1;
    const unsigned short* a1p0 = A1 + (size_t)am0 * K + cc0;
    const unsigned short* a1p1 = A1 + (size_t)am1 * K + cc0;
    const unsigned short* a2p0 = A2 + (size_t)am0 * K + cc0;
    const unsigned short* a2p1 = A2 + (size_t)am1 * K + cc0;
    const unsigned short* w1p0 = W1 + (size_t)(n0 + r0) * K + cc0;
    const unsigned short* w1p1 = W1 + (size_t)(n0 + r0 + 64) * K + cc0;
    const unsigned short* w2p0 = W2 + (size_t)(n0 + r0) * K + cc0;
    const unsigned short* w2p1 = W2 + (size_t)(n0 + r0 + 64) * K + cc0;

    f32x4_t acc1[4][4], acc2[4][4];
#pragma unroll
    for (int a = 0; a < 4; ++a)
#pragma unroll
        for (int bb = 0; bb < 4; ++bb) { acc1[a][bb] = zero4(); acc2[a][bb] = zero4(); }

    auto stage = [&](int buf) {
        gload_lds16(a1p0, &A1s[buf][wave * 512]);
        gload_lds16(a1p1, &A1s[buf][2048 + wave * 512]);
        gload_lds16(a2p0, &A2s[buf][wave * 512]);
        gload_lds16(a2p1, &A2s[buf][2048 + wave * 512]);
        gload_lds16(w1p0, &B1s[buf][wave * 512]);
        gload_lds16(w1p1, &B1s[buf][2048 + wave * 512]);
        gload_lds16(w2p0, &B2s[buf][wave * 512]);
        gload_lds16(w2p1, &B2s[buf][2048 + wave * 512]);
        a1p0 += 32; a1p1 += 32; a2p0 += 32; a2p1 += 32;
        w1p0 += 32; w1p1 += 32; w2p0 += 32; w2p1 += 32;
    };

    stage(0);
    const int NIT = K >> 5;
    for (int it = 0; it < NIT; ++it) {
        const int cur = it & 1;
        __syncthreads();
        if (it + 1 < NIT) stage(cur ^ 1);
        bf16x8_t x1f[4], w1f[4];
#pragma unroll
        for (int bb = 0; bb < 4; ++bb)
            x1f[bb] = *(const bf16x8_t*)&A1s[cur][(wm + bb * 16 + m16) * 32 + g4 * 8];
#pragma unroll
        for (int a = 0; a < 4; ++a)
            w1f[a] = *(const bf16x8_t*)&B1s[cur][(wn + a * 16 + m16) * 32 + g4 * 8];
#pragma unroll
        for (int a = 0; a < 4; ++a)
#pragma unroll
            for (int bb = 0; bb < 4; ++bb)
                acc1[a][bb] = __builtin_amdgcn_mfma_f32_16x16x32_bf16(w1f[a], x1f[bb], acc1[a][bb], 0, 0, 0);
        bf16x8_t x2f[4], w2f[4];
#pragma unroll
        for (int bb = 0; bb < 4; ++bb)
            x2f[bb] = *(const bf16x8_t*)&A2s[cur][(wm + bb * 16 + m16) * 32 + g4 * 8];
#pragma unroll
        for (int a = 0; a < 4; ++a)
            w2f[a] = *(const bf16x8_t*)&B2s[cur][(wn + a * 16 + m16) * 32 + g4 * 8];
#pragma unroll
        for (int a = 0; a < 4; ++a)
#pragma unroll
            for (int bb = 0; bb < 4; ++bb)
                acc2[a][bb] = __builtin_amdgcn_mfma_f32_16x16x32_bf16(w2f[a], x2f[bb], acc2[a][bb], 0, 0, 0);
    }

    const float gt = gate[0];
#pragma unroll
    for (int a = 0; a < 4; ++a) {
        const int cb = n0 + wn + a * 16 + g4 * 4;
        const float4 b1v = *(const float4*)(b1 + cb);
        const float4 b2v = *(const float4*)(b2 + cb);
        const float4 g2  = *(const float4*)(g2v + cb);
#pragma unroll
        for (int bb = 0; bb < 4; ++bb) {
            const int r = m0 + wm + bb * 16 + m16;
            if (r < M) {
                const size_t idx = (size_t)r * N + cb;
                float4 res = *(const float4*)(resid + idx);
                float4 o;
                o.x = res.x + g2.x * (acc1[a][bb][0] + b1v.x) + gt * (acc2[a][bb][0] + b2v.x);
                o.y = res.y + g2.y * (acc1[a][bb][1] + b1v.y) + gt * (acc2[a][bb][1] + b2v.y);
                o.z = res.z + g2.z * (acc1[a][bb][2] + b1v.z) + gt * (acc2[a][bb][2] + b2v.z);
                o.w = res.w + g2.w * (acc1[a][bb][3] + b1v.w) + gt * (acc2[a][bb][3] + b2v.w);
                *(float4*)(out + idx) = o;
            }
        }
    }
}

// ---------------------------------------------------------------------------
// V^T pre-transpose with baked PV key-permutation.
// ---------------------------------------------------------------------------
__global__ __launch_bounds__(256) void vtrans_kernel(const unsigned short* __restrict__ qkv,
                                                     unsigned short* __restrict__ vt) {
    __shared__ unsigned short Vs[64 * 64];
    const int stile = blockIdx.x;   // 0..17
    const int bh = blockIdx.y;
    const int b = bh >> 4, h = bh & 15;
    const int tid = threadIdx.x;
#pragma unroll
    for (int j = 0; j < 2; ++j) {
        int c = j * 256 + tid;
        int r = c >> 3, d8 = (c & 7) * 8;
        int s = stile * 64 + r;
        uint4 v = {0u, 0u, 0u, 0u};
        if (s < Sv) v = *(const uint4*)(qkv + ((size_t)(b * Sv + s) * 3 + 2) * Cv + h * 64 + d8);
        *(uint4*)&Vs[r * 64 + d8] = v;
    }
    __syncthreads();
    const int d  = tid >> 2;
    const int p0 = (tid & 3) * 16;
    unsigned short tmp[16];
#pragma unroll
    for (int e = 0; e < 16; ++e) {
        int p = p0 + e;
        int s_local = (p & 32) + 16 * ((p >> 2) & 1) + 4 * ((p & 31) >> 3) + (p & 3);
        tmp[e] = Vs[s_local * 64 + d];
    }
    unsigned short* dst = vt + ((size_t)bh * 64 + d) * SPADv + stile * 64 + p0;
    *(uint4*)dst       = *(const uint4*)&tmp[0];
    *(uint4*)(dst + 8) = *(const uint4*)&tmp[8];
}

// ---------------------------------------------------------------------------
// Flash attention, S^T formulation (as round 1, cleaned).
// ---------------------------------------------------------------------------
__global__ __launch_bounds__(256) void attn_kernel(const unsigned short* __restrict__ qkv,
                                                   const unsigned short* __restrict__ vt,
                                                   unsigned short* __restrict__ o) {
    __shared__ unsigned short Qs[64 * 64];
    __shared__ unsigned short Ks[2][64 * 64];
    __shared__ unsigned short Vts[2][64 * 64];

    const int tid  = threadIdx.x;
    const int lane = tid & 63;
    const int wave = tid >> 6;
    const int m16  = lane & 15;
    const int g4   = lane >> 4;
    const int qt = blockIdx.x;
    const int bh = blockIdx.y;
    const int b = bh >> 4, h = bh & 15;

    const int lr = lane >> 3;
    const int csw = ((lane & 7) ^ lr) * 8;
    const int sw7 = m16 & 7;

#pragma unroll
    for (int j = 0; j < 2; ++j) {
        int r = wave * 16 + j * 8 + lr;
        int s = Iv + qt * 64 + r;
        gload_lds16(qkv + ((size_t)(b * Sv + s) * 3) * Cv + h * 64 + csw,
                    &Qs[(wave * 16 + j * 8) * 64]);
    }

    auto stage_kv = [&](int st, int buf) {
#pragma unroll
        for (int j = 0; j < 2; ++j) {
            int r = wave * 16 + j * 8 + lr;
            int s = st * 64 + r; if (s > Sv - 1) s = Sv - 1;
            gload_lds16(qkv + ((size_t)(b * Sv + s) * 3 + 1) * Cv + h * 64 + csw,
                        &Ks[buf][(wave * 16 + j * 8) * 64]);
            gload_lds16(vt + ((size_t)bh * 64 + r) * SPADv + st * 64 + csw,
                        &Vts[buf][(wave * 16 + j * 8) * 64]);
        }
    };

    f32x4_t oacc[4];
#pragma unroll
    for (int dt = 0; dt < 4; ++dt) oacc[dt] = zero4();
    float m_run = -1e30f, l_run = 0.f;

    stage_kv(0, 0);
    __syncthreads();

    const bf16x8_t qf0 = *(const bf16x8_t*)&Qs[(wave * 16 + m16) * 64 + ((g4 ^ sw7) * 8)];
    const bf16x8_t qf1 = *(const bf16x8_t*)&Qs[(wave * 16 + m16) * 64 + (((4 + g4) ^ sw7) * 8)];

    const int NT = (Sv + 63) / 64;   // 18
    for (int st = 0; st < NT; ++st) {
        const int cur = st & 1;
        if (st + 1 < NT) stage_kv(st + 1, cur ^ 1);

        f32x4_t sc[4];
#pragma unroll
        for (int kt = 0; kt < 4; ++kt) {
            bf16x8_t k0 = *(const bf16x8_t*)&Ks[cur][(kt * 16 + m16) * 64 + ((g4 ^ sw7) * 8)];
            bf16x8_t k1 = *(const bf16x8_t*)&Ks[cur][(kt * 16 + m16) * 64 + (((4 + g4) ^ sw7) * 8)];
            f32x4_t z = zero4();
            z = __builtin_amdgcn_mfma_f32_16x16x32_bf16(k0, qf0, z, 0, 0, 0);
            z = __builtin_amdgcn_mfma_f32_16x16x32_bf16(k1, qf1, z, 0, 0, 0);
            sc[kt] = z;
        }

        float mx = -1e30f;
#pragma unroll
        for (int kt = 0; kt < 4; ++kt)
#pragma unroll
            for (int r = 0; r < 4; ++r) {
                int key = st * 64 + kt * 16 + g4 * 4 + r;
                float v = sc[kt][r] * 0.125f;
                v = (key < Sv) ? v : -1e30f;
                sc[kt][r] = v;
                mx = fmaxf(mx, v);
            }
        mx = fmaxf(mx, __shfl_xor(mx, 16));
        mx = fmaxf(mx, __shfl_xor(mx, 32));
        const float mnew  = fmaxf(m_run, mx);
        const float alpha = __expf(m_run - mnew);
        m_run = mnew;
        float sum = 0.f;
#pragma unroll
        for (int kt = 0; kt < 4; ++kt)
#pragma unroll
            for (int r = 0; r < 4; ++r) {
                float p = __expf(sc[kt][r] - mnew);
                sc[kt][r] = p;
                sum += p;
            }
        sum += __shfl_xor(sum, 16);
        sum += __shfl_xor(sum, 32);
        l_run = l_run * alpha + sum;
#pragma unroll
        for (int dt = 0; dt < 4; ++dt) oacc[dt] *= alpha;

        us8_t pu0, pu1;
#pragma unroll
        for (int j = 0; j < 8; ++j) {
            pu0[j] = f2bf(sc[(j >> 2)][j & 3]);
            pu1[j] = f2bf(sc[2 + (j >> 2)][j & 3]);
        }
        const bf16x8_t pf0 = __builtin_bit_cast(bf16x8_t, pu0);
        const bf16x8_t pf1 = __builtin_bit_cast(bf16x8_t, pu1);

#pragma unroll
        for (int dt = 0; dt < 4; ++dt) {
            bf16x8_t v0 = *(const bf16x8_t*)&Vts[cur][(dt * 16 + m16) * 64 + ((g4 ^ sw7) * 8)];
            bf16x8_t v1 = *(const bf16x8_t*)&Vts[cur][(dt * 16 + m16) * 64 + (((4 + g4) ^ sw7) * 8)];
            oacc[dt] = __builtin_amdgcn_mfma_f32_16x16x32_bf16(v0, pf0, oacc[dt], 0, 0, 0);
            oacc[dt] = __builtin_amdgcn_mfma_f32_16x16x32_bf16(v1, pf1, oacc[dt], 0, 0, 0);
        }
        __syncthreads();
    }

    const float inv = 1.0f / l_run;
    const int q = qt * 64 + wave * 16 + m16;
    const size_t row = (size_t)(b * Nv + q) * Cv + h * 64;
#pragma unroll
    for (int dt = 0; dt < 4; ++dt) {
        ushort4 o4 = {f2bf(oacc[dt][0] * inv), f2bf(oacc[dt][1] * inv),
                      f2bf(oacc[dt][2] * inv), f2bf(oacc[dt][3] * inv)};
        *(ushort4*)&o[row + dt * 16 + g4 * 4] = o4;
    }
}

// ---------------------------------------------------------------------------
// Launcher
// ---------------------------------------------------------------------------
extern "C" void kernel_launch(void* const* d_in, const int* in_sizes, int n_in,
                              void* d_out, int out_size, void* d_ws, size_t ws_size,
                              hipStream_t stream) {
    (void)in_sizes; (void)n_in; (void)out_size; (void)ws_size;
    const float* x       = (const float*)d_in[0];
    const float* instr   = (const float*)d_in[1];
    const float* norm1_w = (const float*)d_in[2];
    const float* norm1_b = (const float*)d_in[3];
    const float* qkv_w   = (const float*)d_in[4];
    const float* q_bias  = (const float*)d_in[5];
    const float* v_bias  = (const float*)d_in[6];
    const float* proj_w  = (const float*)d_in[7];
    const float* proj_b  = (const float*)d_in[8];
    const float* gamma_1 = (const float*)d_in[9];
    const float* gamma_2 = (const float*)d_in[10];
    const float* norm2_w = (const float*)d_in[11];
    const float* norm2_b = (const float*)d_in[12];
    const float* fc1_w   = (const float*)d_in[13];
    const float* fc1_b   = (const float*)d_in[14];
    const float* fc2_w   = (const float*)d_in[15];
    const float* fc2_b   = (const float*)d_in[16];
    const float* pfc1_w  = (const float*)d_in[17];
    const float* pfc1_b  = (const float*)d_in[18];
    const float* pfc2_w  = (const float*)d_in[19];
    const float* pfc2_b  = (const float*)d_in[20];
    const float* gate    = (const float*)d_in[21];
    const float* ir_ln_w = (const float*)d_in[22];
    const float* ir_ln_b = (const float*)d_in[23];
    const float* ir_l1_w = (const float*)d_in[24];
    const float* ir_l1_b = (const float*)d_in[25];
    const float* ir_l2_w = (const float*)d_in[26];
    const float* ir_l2_b = (const float*)d_in[27];
    float* out = (float*)d_out;

    char* ws = (char*)d_ws;
    size_t off = 0;
    auto alloc = [&](size_t bytes) -> char* {
        char* p = ws + off;
        off += (bytes + 255) & ~(size_t)255;
        return p;
    };
    unsigned short* w_qkv  = (unsigned short*)alloc((size_t)3 * Cv * Cv * 2);
    unsigned short* w_proj = (unsigned short*)alloc((size_t)Cv * Cv * 2);
    unsigned short* w_fc1  = (unsigned short*)alloc((size_t)HIDv * Cv * 2);
    unsigned short* w_fc2  = (unsigned short*)alloc((size_t)Cv * HIDv * 2);
    unsigned short* w_pfc1 = (unsigned short*)alloc((size_t)HIDv * Cv * 2);
    unsigned short* w_pfc2 = (unsigned short*)alloc((size_t)Cv * HIDv * 2);
    unsigned short* w_ir1  = (unsigned short*)alloc((size_t)Cv * IDv * 2);
    unsigned short* w_ir2  = (unsigned short*)alloc((size_t)Cv * Cv * 2);
    float*          qkvb   = (float*)alloc((size_t)3 * Cv * 4);
    unsigned short* irln   = (unsigned short*)alloc((size_t)BIv * IDv * 2);
    unsigned short* h1     = (unsigned short*)alloc((size_t)BIv * Cv * 2);
    unsigned short* kvtmp  = (unsigned short*)alloc((size_t)BIv * Cv * 2);
    unsigned short* cat    = (unsigned short*)alloc((size_t)BSv * Cv * 2);
    unsigned short* qkvbuf = (unsigned short*)alloc((size_t)BSv * 3 * Cv * 2);
    unsigned short* obuf   = (unsigned short*)alloc((size_t)BNv * Cv * 2);
    float*          x1     = (float*)alloc((size_t)BNv * Cv * 4);
    unsigned short* ybuf   = (unsigned short*)alloc((size_t)BNv * Cv * 2);
    unsigned short* gbuf1  = (unsigned short*)alloc((size_t)BNv * HIDv * 2);
    // vt aliases gbuf1 (only live between vtrans and attn, before fc1)
    unsigned short* vt     = gbuf1;
    // gbuf2 aliases cat+qkvbuf (both dead by LN2): 9.0+27.1 MB >= 32 MB
    unsigned short* gbuf2  = cat;

    cvt8_kernel<<<22272, 256, 0, stream>>>(qkv_w, proj_w, fc1_w, fc2_w, pfc1_w, pfc2_w,
                                           ir_l1_w, ir_l2_w,
                                           w_qkv, w_proj, w_fc1, w_fc2, w_pfc1, w_pfc2,
                                           w_ir1, w_ir2);

    build_qkvb_kernel<<<12, 256, 0, stream>>>(q_bias, v_bias, qkvb);

    // instruct branch: LN -> Linear+GELU -> Linear
    ln_kernel<<<BIv, 256, 0, stream>>>(instr, ir_ln_w, ir_ln_b, irln,
                                       IDv, 1.0f / IDv, 1 << 28, 0, 0);
    // LN1 writes directly into cat rows b*S + I + n
    ln_kernel<<<BNv, 256, 0, stream>>>(x, norm1_w, norm1_b, cat,
                                       Cv, 1.0f / Cv, Nv, Sv, Iv);
    gemm_bf16_kernel<1><<<dim3(Cv / 128, (BIv + 127) / 128), 256, 0, stream>>>(
        irln, w_ir1, ir_l1_b, h1, nullptr, nullptr, BIv, Cv, IDv);
    gemm_bf16_kernel<0><<<dim3(Cv / 128, (BIv + 127) / 128), 256, 0, stream>>>(
        h1, w_ir2, ir_l2_b, kvtmp, nullptr, nullptr, BIv, Cv, Cv);
    scatter_kv_kernel<<<BIv, 256, 0, stream>>>(kvtmp, cat);

    // QKV projection over cat [BS, C] -> [BS, 3C]
    gemm_bf16_kernel<0><<<dim3(3 * Cv / 128, (BSv + 127) / 128), 256, 0, stream>>>(
        cat, w_qkv, qkvb, qkvbuf, nullptr, nullptr, BSv, 3 * Cv, Cv);

    // V^T pre-transpose (permuted), then attention
    vtrans_kernel<<<dim3(18, Bv * Hv), 256, 0, stream>>>(qkvbuf, vt);
    attn_kernel<<<dim3(Nv / 64, Bv * Hv), 256, 0, stream>>>(qkvbuf, vt, obuf);

    // proj + LayerScale residual: x1 = x + gamma_1*(o@proj^T + b)
    gemm_bf16_kernel<2><<<dim3(Cv / 128, BNv / 128), 256, 0, stream>>>(
        obuf, w_proj, proj_b, x1, x, gamma_1, BNv, Cv, Cv);

    // LN2
    ln_kernel<<<BNv, 256, 0, stream>>>(x1, norm2_w, norm2_b, ybuf,
                                       Cv, 1.0f / Cv, 1 << 28, 0, 0);

    // fused fc1 + pfc1 (shared A): gbuf1 = gelu(y@fc1+b), gbuf2 = gelu(y@pfc1+b)
    gemm_dualw_kernel<<<dim3(HIDv / 128, BNv / 128), 256, 0, stream>>>(
        ybuf, w_fc1, w_pfc1, fc1_b, pfc1_b, gbuf1, gbuf2, BNv, HIDv, Cv);

    // fused fc2 + pfc2: out = x1 + gamma_2*(g1@fc2+b) + gate*(g2@pfc2+b)
    gemm_dualab_kernel<<<dim3(Cv / 128, BNv / 128), 256, 0, stream>>>(
        gbuf1, gbuf2, w_fc2, w_pfc2, fc2_b, pfc2_b, x1, gamma_2, gate, out,
        BNv, Cv, HIDv);
}